// Round 1
// baseline (1041.267 us; speedup 1.0000x reference)
//
#include <hip/hip_runtime.h>
#include <stdint.h>

// DiscreteMarkovDynamics: 5-step Markov jump simulation, B=32, L=4096, V=512.
// Key insight: intensity depends on x only through its value -> precompute
// I[512][512] table once (kernel A), then one wave per position runs all 5
// steps (kernel B). PRNG = JAX threefry2x32, partitionable scheme (default
// since JAX 0.4.30): bits[f] = w0^w1 of threefry(key, (0, f)).

#define VOCAB 512
#define EMB   256
#define HID   64
#define NPOS  (32 * 4096)   // B*L = 131072
#define STEPS 5

// Exact mirror of jax._src.prng.threefry2x32 (20 rounds).
__host__ __device__ __forceinline__ void tf2x32(uint32_t k0, uint32_t k1,
                                                uint32_t x0, uint32_t x1,
                                                uint32_t& o0, uint32_t& o1) {
  uint32_t ks2 = k0 ^ k1 ^ 0x1BD11BDAu;
  x0 += k0; x1 += k1;
#define TFR(r) { x0 += x1; x1 = (x1 << (r)) | (x1 >> (32 - (r))); x1 ^= x0; }
  TFR(13) TFR(15) TFR(26) TFR(6)
  x0 += k1;  x1 += ks2 + 1u;
  TFR(17) TFR(29) TFR(16) TFR(24)
  x0 += ks2; x1 += k0 + 2u;
  TFR(13) TFR(15) TFR(26) TFR(6)
  x0 += k0;  x1 += k1 + 3u;
  TFR(17) TFR(29) TFR(16) TFR(24)
  x0 += k1;  x1 += ks2 + 4u;
  TFR(13) TFR(15) TFR(26) TFR(6)
  x0 += ks2; x1 += k0 + 5u;
#undef TFR
  o0 = x0; o1 = x1;
}

struct Keys {
  uint32_t k1a[STEPS], k1b[STEPS];  // categorical (gumbel) keys per step
  uint32_t k2a[STEPS], k2b[STEPS];  // accept-uniform keys per step
};

// Kernel A: I[s][v] = relu(emb[s] @ W1 + b1) @ W2 + b2, fp64 accumulation
// (<= 1 ulp of exact; ref's fp32 BLAS is within ~1e-6 rel of the same value).
__global__ void build_table(const float* __restrict__ emb,
                            const float* __restrict__ W1,
                            const float* __restrict__ b1,
                            const float* __restrict__ W2,
                            const float* __restrict__ b2,
                            float* __restrict__ I) {
  const int s = blockIdx.x;     // state 0..511
  const int lane = threadIdx.x; // 64 threads = HID
  __shared__ float h[HID];
  const float* e = emb + s * EMB;
  double acc = 0.0;
  for (int k = 0; k < EMB; ++k)
    acc += (double)e[k] * (double)W1[k * HID + lane];
  float m = (float)acc + b1[lane];      // fp32 add of b1, mirrors ref order
  h[lane] = m > 0.0f ? m : 0.0f;        // relu
  __syncthreads();
  for (int j = 0; j < VOCAB / HID; ++j) {
    const int v = lane + HID * j;       // coalesced
    double a2 = 0.0;
    for (int k = 0; k < HID; ++k)
      a2 += (double)h[k] * (double)W2[k * VOCAB + v];
    I[s * VOCAB + v] = (float)a2 + b2[v];  // fp32 add of b2
  }
}

// Kernel B: one wave (64 lanes) per position, all 5 steps fused.
__global__ __launch_bounds__(256)
void markov_kernel(const int* __restrict__ x_in,
                   const float* __restrict__ I,
                   int* __restrict__ x_out,
                   Keys K) {
  const int gtid = blockIdx.x * blockDim.x + threadIdx.x;
  const int pos  = gtid >> 6;
  const int lane = gtid & 63;
  if (pos >= NPOS) return;

  int s = x_in[pos];
  const float TINYF = 1.17549435e-38f;  // finfo(f32).tiny, gumbel uniform minval

#pragma unroll
  for (int t = 0; t < STEPS; ++t) {
    const float* row = I + s * VOCAB;
    float best = -__builtin_inff();
    int bidx = 0;
    const uint32_t fbase = ((uint32_t)pos << 9) + (uint32_t)lane;  // flat idx

#pragma unroll
    for (int j = 0; j < VOCAB / 64; ++j) {
      const int v = lane + (j << 6);              // coalesced row reads
      uint32_t w0, w1;
      tf2x32(K.k1a[t], K.k1b[t], 0u, fbase + ((uint32_t)j << 6), w0, w1);
      const uint32_t bits = w0 ^ w1;              // partitionable 32-bit draw
      float uf = __uint_as_float((bits >> 9) | 0x3f800000u) - 1.0f;
      if (uf == 0.0f) uf = TINYF;                 // floats + tiny, then max(tiny,.)
      const float g = -logf(-logf(uf));           // gumbel
      if (v != s) {                               // self-transition masked -inf
        const float val = row[v] + g;
        if (val > best) { best = val; bidx = v; } // strict > keeps first index
      }
    }
    // wave argmax butterfly; tiebreak: lower index (jnp.argmax = first max)
    for (int off = 32; off > 0; off >>= 1) {
      const float ob = __shfl_xor(best, off, 64);
      const int   oi = __shfl_xor(bidx, off, 64);
      if (ob > best || (ob == best && oi < bidx)) { best = ob; bidx = oi; }
    }

    const float rate = row[bidx];                 // unmasked intensity
    uint32_t w0, w1;
    tf2x32(K.k2a[t], K.k2b[t], 0u, (uint32_t)pos, w0, w1);
    const uint32_t ub = w0 ^ w1;
    const float u = __uint_as_float((ub >> 9) | 0x3f800000u) - 1.0f;
    const float z = (-rate) * 0.01f;              // dt = 0.05/5 as fp32
    // fp64 exp then round -> correctly-rounded fp32 exp (matches glibc expf)
    const float p = 1.0f - (float)exp((double)z);
    if (u < p) s = bidx;
  }

  if (lane == 0) x_out[pos] = s;
}

extern "C" void kernel_launch(void* const* d_in, const int* in_sizes, int n_in,
                              void* d_out, int out_size, void* d_ws, size_t ws_size,
                              hipStream_t stream) {
  const int*   x   = (const int*)d_in[0];
  const float* emb = (const float*)d_in[1];
  const float* W1  = (const float*)d_in[2];
  const float* b1  = (const float*)d_in[3];
  const float* W2  = (const float*)d_in[4];
  const float* b2  = (const float*)d_in[5];
  // d_in[6] = steps (always 5; baked in as STEPS)
  float* I = (float*)d_ws;          // 512*512*4 = 1 MiB scratch
  int* out = (int*)d_out;

  // Host-side key derivation, partitionable scheme:
  //   key(42) = (0,42); split(key,5)[t] = threefry(key,(0,t));
  //   (k1,k2) = split(S_t): k_j = threefry(S_t,(0,j)).
  Keys K;
  for (int t = 0; t < STEPS; ++t) {
    uint32_t Sa, Sb;
    tf2x32(0u, 42u, 0u, (uint32_t)t, Sa, Sb);
    tf2x32(Sa, Sb, 0u, 0u, K.k1a[t], K.k1b[t]);
    tf2x32(Sa, Sb, 0u, 1u, K.k2a[t], K.k2b[t]);
  }

  build_table<<<VOCAB, HID, 0, stream>>>(emb, W1, b1, W2, b2, I);
  markov_kernel<<<(NPOS * 64) / 256, 256, 0, stream>>>(x, I, out, K);
}

// Round 2
// 249.644 us; speedup vs baseline: 4.1710x; 4.1710x over previous
//
#include <hip/hip_runtime.h>
#include <stdint.h>

// DiscreteMarkovDynamics: 5-step Markov jump sim, B=32, L=4096, V=512.
// R1: table precompute + wave-per-position categorical -> 1024 us, VALU-bound.
// R2: provable-reject skip. pthr[s] = 1-exp(-rowmax*dt) computed with the
// IDENTICAL op chain as the accept prob; rowmax >= rate and every op is
// monotone under fp rounding, so u >= pthr[s] guarantees u >= p(rate) ->
// reject -> the 512-draw categorical is dead code for ~97.8% of steps.

#define VOCAB 512
#define EMB   256
#define HID   64
#define NPOS  (32 * 4096)   // B*L = 131072
#define STEPS 5
#define PPW   16            // positions per wave
#define NWAVES (NPOS / PPW) // 8192 = exactly 256 CU x 32 waves resident

// Exact mirror of jax._src.prng.threefry2x32 (20 rounds).
__host__ __device__ __forceinline__ void tf2x32(uint32_t k0, uint32_t k1,
                                                uint32_t x0, uint32_t x1,
                                                uint32_t& o0, uint32_t& o1) {
  uint32_t ks2 = k0 ^ k1 ^ 0x1BD11BDAu;
  x0 += k0; x1 += k1;
#define TFR(r) { x0 += x1; x1 = (x1 << (r)) | (x1 >> (32 - (r))); x1 ^= x0; }
  TFR(13) TFR(15) TFR(26) TFR(6)
  x0 += k1;  x1 += ks2 + 1u;
  TFR(17) TFR(29) TFR(16) TFR(24)
  x0 += ks2; x1 += k0 + 2u;
  TFR(13) TFR(15) TFR(26) TFR(6)
  x0 += k0;  x1 += k1 + 3u;
  TFR(17) TFR(29) TFR(16) TFR(24)
  x0 += k1;  x1 += ks2 + 4u;
  TFR(13) TFR(15) TFR(26) TFR(6)
  x0 += ks2; x1 += k0 + 5u;
#undef TFR
  o0 = x0; o1 = x1;
}

struct Keys {
  uint32_t k1a[STEPS], k1b[STEPS];  // categorical (gumbel) keys per step
  uint32_t k2a[STEPS], k2b[STEPS];  // accept-uniform keys per step
};

// Kernel A: I[s][v] = relu(emb[s] @ W1 + b1) @ W2 + b2, fp64 accumulation,
// plus pthr[s] = 1-exp(-rowmax*0.01f) via the accept-path op chain.
__global__ void build_table(const float* __restrict__ emb,
                            const float* __restrict__ W1,
                            const float* __restrict__ b1,
                            const float* __restrict__ W2,
                            const float* __restrict__ b2,
                            float* __restrict__ I,
                            float* __restrict__ pthr) {
  const int s = blockIdx.x;     // state 0..511
  const int lane = threadIdx.x; // 64 threads = HID
  __shared__ float h[HID];
  const float* e = emb + s * EMB;
  // 4 partial fp64 accumulators (break the 256-long dependent chain;
  // fp64 reorder error ~1e-13 rel << f32 ulp, negligible flip risk)
  double a0 = 0.0, a1 = 0.0, a2 = 0.0, a3 = 0.0;
  for (int k = 0; k < EMB; k += 4) {
    a0 += (double)e[k + 0] * (double)W1[(k + 0) * HID + lane];
    a1 += (double)e[k + 1] * (double)W1[(k + 1) * HID + lane];
    a2 += (double)e[k + 2] * (double)W1[(k + 2) * HID + lane];
    a3 += (double)e[k + 3] * (double)W1[(k + 3) * HID + lane];
  }
  float m = (float)((a0 + a1) + (a2 + a3)) + b1[lane];
  h[lane] = m > 0.0f ? m : 0.0f;        // relu
  __syncthreads();
  float lmax = -__builtin_inff();
  for (int j = 0; j < VOCAB / HID; ++j) {
    const int v = lane + HID * j;       // coalesced
    double acc = 0.0;
    for (int k = 0; k < HID; ++k)
      acc += (double)h[k] * (double)W2[k * VOCAB + v];
    const float val = (float)acc + b2[v];
    I[s * VOCAB + v] = val;
    lmax = fmaxf(lmax, val);
  }
  for (int off = 32; off > 0; off >>= 1)
    lmax = fmaxf(lmax, __shfl_xor(lmax, off, 64));
  if (lane == 0) {
    const float z = (-lmax) * 0.01f;              // same chain as accept path
    pthr[s] = 1.0f - (float)exp((double)z);       // monotone => safe bound
  }
}

// Kernel B: one wave per 16 positions; per step a cheap provable-reject
// check; full wave-parallel categorical only when u < pthr[s] (~2.2%).
__global__ __launch_bounds__(256)
void markov_kernel(const int* __restrict__ x_in,
                   const float* __restrict__ I,
                   const float* __restrict__ pthr,
                   int* __restrict__ x_out,
                   Keys K) {
  const int gtid = blockIdx.x * blockDim.x + threadIdx.x;
  const int wave = gtid >> 6;
  const int lane = gtid & 63;
  const int base = wave * PPW;
  const float TINYF = 1.17549435e-38f;

  // Phase 1: accept uniforms u[p][t], flat q = p*5+t in [0,80).
  // Lane l holds q=l in r0 and q=l+64 in r1 (l<16).
  float r0, r1 = 0.0f;
  {
    uint32_t w0, w1;
    int q = lane, p = q / 5, t = q % 5;
    tf2x32(K.k2a[t], K.k2b[t], 0u, (uint32_t)(base + p), w0, w1);
    r0 = __uint_as_float((((w0 ^ w1) >> 9) | 0x3f800000u)) - 1.0f;
    q = lane + 64;
    if (q < PPW * STEPS) {
      p = q / 5; t = q % 5;
      tf2x32(K.k2a[t], K.k2b[t], 0u, (uint32_t)(base + p), w0, w1);
      r1 = __uint_as_float((((w0 ^ w1) >> 9) | 0x3f800000u)) - 1.0f;
    }
  }
  const int sload = (lane < PPW) ? x_in[base + lane] : 0;
  int result = 0;

  for (int p = 0; p < PPW; ++p) {
    int s = __shfl(sload, p, 64);
    s = __builtin_amdgcn_readfirstlane(s);   // uniform -> scalar addressing
#pragma unroll
    for (int t = 0; t < STEPS; ++t) {
      const int q = p * STEPS + t;
      const float u = (q < 64) ? __shfl(r0, q, 64) : __shfl(r1, q - 64, 64);
      if (u >= pthr[s]) continue;            // provable reject (wave-uniform)

      // Full categorical (rare, ~2.2% of pos-steps; byte-identical to R1)
      const float* row = I + s * VOCAB;
      float best = -__builtin_inff();
      int bidx = 0;
      const uint32_t fbase = ((uint32_t)(base + p) << 9) + (uint32_t)lane;
#pragma unroll
      for (int j = 0; j < VOCAB / 64; ++j) {
        const int v = lane + (j << 6);
        uint32_t w0, w1;
        tf2x32(K.k1a[t], K.k1b[t], 0u, fbase + ((uint32_t)j << 6), w0, w1);
        const uint32_t bits = w0 ^ w1;
        float uf = __uint_as_float((bits >> 9) | 0x3f800000u) - 1.0f;
        if (uf == 0.0f) uf = TINYF;
        const float g = -logf(-logf(uf));
        if (v != s) {
          const float val = row[v] + g;
          if (val > best) { best = val; bidx = v; }
        }
      }
      for (int off = 32; off > 0; off >>= 1) {
        const float ob = __shfl_xor(best, off, 64);
        const int   oi = __shfl_xor(bidx, off, 64);
        if (ob > best || (ob == best && oi < bidx)) { best = ob; bidx = oi; }
      }
      bidx = __builtin_amdgcn_readfirstlane(bidx);
      const float rate = row[bidx];
      const float z = (-rate) * 0.01f;
      const float pacc = 1.0f - (float)exp((double)z);  // CR fp32 exp
      if (u < pacc) { s = bidx; }
    }
    result = (lane == p) ? s : result;       // p < 16 <= 63
  }
  if (lane < PPW) x_out[base + lane] = result;
}

extern "C" void kernel_launch(void* const* d_in, const int* in_sizes, int n_in,
                              void* d_out, int out_size, void* d_ws, size_t ws_size,
                              hipStream_t stream) {
  const int*   x   = (const int*)d_in[0];
  const float* emb = (const float*)d_in[1];
  const float* W1  = (const float*)d_in[2];
  const float* b1  = (const float*)d_in[3];
  const float* W2  = (const float*)d_in[4];
  const float* b2  = (const float*)d_in[5];
  float* I    = (float*)d_ws;                      // 1 MiB
  float* pthr = (float*)d_ws + VOCAB * VOCAB;      // +2 KiB
  int* out = (int*)d_out;

  // Host-side key derivation (partitionable scheme):
  //   key(42) = (0,42); split -> S_t = tf(key,(0,t)); (k1,k2) = tf(S_t,(0,j))
  Keys K;
  for (int t = 0; t < STEPS; ++t) {
    uint32_t Sa, Sb;
    tf2x32(0u, 42u, 0u, (uint32_t)t, Sa, Sb);
    tf2x32(Sa, Sb, 0u, 0u, K.k1a[t], K.k1b[t]);
    tf2x32(Sa, Sb, 0u, 1u, K.k2a[t], K.k2b[t]);
  }

  build_table<<<VOCAB, HID, 0, stream>>>(emb, W1, b1, W2, b2, I, pthr);
  markov_kernel<<<(NWAVES * 64) / 256, 256, 0, stream>>>(x, I, pthr, out, K);
}

// Round 3
// 125.609 us; speedup vs baseline: 8.2897x; 1.9875x over previous
//
#include <hip/hip_runtime.h>
#include <stdint.h>

// DiscreteMarkovDynamics: 5-step Markov jump sim, B=32, L=4096, V=512.
// R1: table precompute + wave-per-position categorical -> 1024 us.
// R2: provable-reject skip (u >= pthr[s] => categorical is dead code) -> 250 us,
//     but build_table became the bottleneck (512 waves, latency-bound, VALUBusy 1%).
// R3: build_table split into 2 kernels @ 2048 waves each, bitwise-identical
//     accumulation order; markov: pthr staged in LDS, PPW 16->8 for tail balance.

#define VOCAB 512
#define EMB   256
#define HID   64
#define NPOS  (32 * 4096)   // B*L = 131072
#define STEPS 5
#define PPW   8             // positions per wave
#define NWAVES (NPOS / PPW) // 16384

// Exact mirror of jax._src.prng.threefry2x32 (20 rounds).
__host__ __device__ __forceinline__ void tf2x32(uint32_t k0, uint32_t k1,
                                                uint32_t x0, uint32_t x1,
                                                uint32_t& o0, uint32_t& o1) {
  uint32_t ks2 = k0 ^ k1 ^ 0x1BD11BDAu;
  x0 += k0; x1 += k1;
#define TFR(r) { x0 += x1; x1 = (x1 << (r)) | (x1 >> (32 - (r))); x1 ^= x0; }
  TFR(13) TFR(15) TFR(26) TFR(6)
  x0 += k1;  x1 += ks2 + 1u;
  TFR(17) TFR(29) TFR(16) TFR(24)
  x0 += ks2; x1 += k0 + 2u;
  TFR(13) TFR(15) TFR(26) TFR(6)
  x0 += k0;  x1 += k1 + 3u;
  TFR(17) TFR(29) TFR(16) TFR(24)
  x0 += k1;  x1 += ks2 + 4u;
  TFR(13) TFR(15) TFR(26) TFR(6)
  x0 += ks2; x1 += k0 + 5u;
#undef TFR
  o0 = x0; o1 = x1;
}

struct Keys {
  uint32_t k1a[STEPS], k1b[STEPS];  // categorical (gumbel) keys per step
  uint32_t k2a[STEPS], k2b[STEPS];  // accept-uniform keys per step
};

// Kernel A1: H[s][hid] = relu(emb[s] . W1[:,hid] + b1[hid]).
// 512 blocks x 256 threads; 4-way split-k with k = kq (mod 4) per group and
// combine (a0+a1)+(a2+a3) -- bitwise identical to R2's 4-accumulator loop.
__global__ __launch_bounds__(256)
void build_h(const float* __restrict__ emb,
             const float* __restrict__ W1,
             const float* __restrict__ b1,
             float* __restrict__ H) {
  const int s   = blockIdx.x;
  const int hid = threadIdx.x & (HID - 1);
  const int kq  = threadIdx.x >> 6;          // 0..3
  const float* e = emb + s * EMB;
  double acc = 0.0;
#pragma unroll 4
  for (int k = kq; k < EMB; k += 4)
    acc += (double)e[k] * (double)W1[k * HID + hid];
  __shared__ double part[4][HID];
  part[kq][hid] = acc;
  __syncthreads();
  if (kq == 0) {
    const double a = (part[0][hid] + part[1][hid]) + (part[2][hid] + part[3][hid]);
    const float m = (float)a + b1[hid];
    H[s * HID + hid] = m > 0.0f ? m : 0.0f;  // relu
  }
}

// Kernel A2: I[s][v] = H[s] . W2[:,v] + b2[v] (serial fp64 k-chain, identical
// order to R2), plus pthr[s] = 1-exp(-rowmax*0.01f) via the accept-path chain.
__global__ __launch_bounds__(256)
void build_table2(const float* __restrict__ W2,
                  const float* __restrict__ b2,
                  const float* __restrict__ H,
                  float* __restrict__ I,
                  float* __restrict__ pthr) {
  const int s   = blockIdx.x;
  const int tid = threadIdx.x;
  __shared__ float h[HID];
  __shared__ float redmax[4];
  if (tid < HID) h[tid] = H[s * HID + tid];
  __syncthreads();
  double acc0 = 0.0, acc1 = 0.0;             // 2 outputs per thread, ILP 2
#pragma unroll 8
  for (int k = 0; k < HID; ++k) {
    const float hk = h[k];
    acc0 += (double)hk * (double)W2[k * VOCAB + tid];
    acc1 += (double)hk * (double)W2[k * VOCAB + tid + 256];
  }
  const float v0 = (float)acc0 + b2[tid];
  const float v1 = (float)acc1 + b2[tid + 256];
  I[s * VOCAB + tid]       = v0;
  I[s * VOCAB + tid + 256] = v1;
  float lmax = fmaxf(v0, v1);                // max is order-insensitive
  for (int off = 32; off > 0; off >>= 1)
    lmax = fmaxf(lmax, __shfl_xor(lmax, off, 64));
  if ((tid & 63) == 0) redmax[tid >> 6] = lmax;
  __syncthreads();
  if (tid == 0) {
    const float m = fmaxf(fmaxf(redmax[0], redmax[1]), fmaxf(redmax[2], redmax[3]));
    const float z = (-m) * 0.01f;            // same chain as accept path
    pthr[s] = 1.0f - (float)exp((double)z);  // monotone => safe reject bound
  }
}

// Kernel B: one wave per 8 positions; per step a cheap provable-reject check
// against LDS-staged pthr; full wave-parallel categorical only when
// u < pthr[s] (~2.2% of pos-steps; byte-identical to R1/R2 path).
__global__ __launch_bounds__(256)
void markov_kernel(const int* __restrict__ x_in,
                   const float* __restrict__ I,
                   const float* __restrict__ pthr,
                   int* __restrict__ x_out,
                   Keys K) {
  __shared__ float sp[VOCAB];
  sp[threadIdx.x]       = pthr[threadIdx.x];
  sp[threadIdx.x + 256] = pthr[threadIdx.x + 256];
  __syncthreads();

  const int gtid = blockIdx.x * blockDim.x + threadIdx.x;
  const int wave = gtid >> 6;
  const int lane = gtid & 63;
  const int base = wave * PPW;
  const float TINYF = 1.17549435e-38f;

  // Phase 1: accept uniforms u[p][t], flat q = p*5+t in [0,40). Lane q holds q.
  float r0 = 0.0f;
  if (lane < PPW * STEPS) {
    const int p = lane / 5, t = lane % 5;
    uint32_t w0, w1;
    tf2x32(K.k2a[t], K.k2b[t], 0u, (uint32_t)(base + p), w0, w1);
    r0 = __uint_as_float((((w0 ^ w1) >> 9) | 0x3f800000u)) - 1.0f;
  }
  const int sload = (lane < PPW) ? x_in[base + lane] : 0;
  int result = 0;

#pragma unroll
  for (int p = 0; p < PPW; ++p) {
    int s = __shfl(sload, p, 64);
    s = __builtin_amdgcn_readfirstlane(s);   // uniform
#pragma unroll
    for (int t = 0; t < STEPS; ++t) {
      const float u = __shfl(r0, p * STEPS + t, 64);
      if (u >= sp[s]) continue;              // provable reject (wave-uniform)

      // Full categorical (rare; byte-identical to R1)
      const float* row = I + s * VOCAB;
      float best = -__builtin_inff();
      int bidx = 0;
      const uint32_t fbase = ((uint32_t)(base + p) << 9) + (uint32_t)lane;
#pragma unroll
      for (int j = 0; j < VOCAB / 64; ++j) {
        const int v = lane + (j << 6);
        uint32_t w0, w1;
        tf2x32(K.k1a[t], K.k1b[t], 0u, fbase + ((uint32_t)j << 6), w0, w1);
        const uint32_t bits = w0 ^ w1;
        float uf = __uint_as_float((bits >> 9) | 0x3f800000u) - 1.0f;
        if (uf == 0.0f) uf = TINYF;
        const float g = -logf(-logf(uf));
        if (v != s) {
          const float val = row[v] + g;
          if (val > best) { best = val; bidx = v; }
        }
      }
      for (int off = 32; off > 0; off >>= 1) {
        const float ob = __shfl_xor(best, off, 64);
        const int   oi = __shfl_xor(bidx, off, 64);
        if (ob > best || (ob == best && oi < bidx)) { best = ob; bidx = oi; }
      }
      bidx = __builtin_amdgcn_readfirstlane(bidx);
      const float rate = row[bidx];
      const float z = (-rate) * 0.01f;
      const float pacc = 1.0f - (float)exp((double)z);  // CR fp32 exp
      if (u < pacc) { s = bidx; }
    }
    result = (lane == p) ? s : result;       // p < 8 <= 63
  }
  if (lane < PPW) x_out[base + lane] = result;
}

extern "C" void kernel_launch(void* const* d_in, const int* in_sizes, int n_in,
                              void* d_out, int out_size, void* d_ws, size_t ws_size,
                              hipStream_t stream) {
  const int*   x   = (const int*)d_in[0];
  const float* emb = (const float*)d_in[1];
  const float* W1  = (const float*)d_in[2];
  const float* b1  = (const float*)d_in[3];
  const float* W2  = (const float*)d_in[4];
  const float* b2  = (const float*)d_in[5];
  float* I    = (float*)d_ws;                        // 1 MiB
  float* pthr = (float*)d_ws + VOCAB * VOCAB;        // +2 KiB
  float* H    = pthr + VOCAB;                        // +128 KiB
  int* out = (int*)d_out;

  // Host-side key derivation (partitionable scheme):
  //   key(42) = (0,42); split -> S_t = tf(key,(0,t)); (k1,k2) = tf(S_t,(0,j))
  Keys K;
  for (int t = 0; t < STEPS; ++t) {
    uint32_t Sa, Sb;
    tf2x32(0u, 42u, 0u, (uint32_t)t, Sa, Sb);
    tf2x32(Sa, Sb, 0u, 0u, K.k1a[t], K.k1b[t]);
    tf2x32(Sa, Sb, 0u, 1u, K.k2a[t], K.k2b[t]);
  }

  build_h<<<VOCAB, 256, 0, stream>>>(emb, W1, b1, H);
  build_table2<<<VOCAB, 256, 0, stream>>>(W2, b2, H, I, pthr);
  markov_kernel<<<(NWAVES * 64) / 256, 256, 0, stream>>>(x, I, pthr, out, K);
}

// Round 4
// 121.466 us; speedup vs baseline: 8.5725x; 1.0341x over previous
//
#include <hip/hip_runtime.h>
#include <stdint.h>

// DiscreteMarkovDynamics: 5-step Markov jump sim, B=32, L=4096, V=512.
// R1: table precompute + wave-per-position categorical -> 1024 us.
// R2: provable-reject skip (u >= pthr[s] => categorical dead code) -> 250 us.
// R3: split/parallel builds, LDS pthr, PPW=8 -> 125 us (markov 57, builds ~60).
// R4: (a) single fused build kernel, 512x512 threads, split-k8 + full-unroll
//     64-chain (latency-hiding, was the hidden bottleneck); (b) markov: all 40
//     accept tests evaluated in ONE ballot (uniforms are lane-parallel, state
//     only changes on rare accepts); loop only over set bits (~0.9/wave),
//     re-ballot a position's future bits on accept.

#define VOCAB 512
#define EMB   256
#define HID   64
#define NPOS  (32 * 4096)   // B*L = 131072
#define STEPS 5
#define PPW   8             // positions per wave; PPW*STEPS=40 <= 64 lanes
#define NWAVES (NPOS / PPW) // 16384

// Exact mirror of jax._src.prng.threefry2x32 (20 rounds).
__host__ __device__ __forceinline__ void tf2x32(uint32_t k0, uint32_t k1,
                                                uint32_t x0, uint32_t x1,
                                                uint32_t& o0, uint32_t& o1) {
  uint32_t ks2 = k0 ^ k1 ^ 0x1BD11BDAu;
  x0 += k0; x1 += k1;
#define TFR(r) { x0 += x1; x1 = (x1 << (r)) | (x1 >> (32 - (r))); x1 ^= x0; }
  TFR(13) TFR(15) TFR(26) TFR(6)
  x0 += k1;  x1 += ks2 + 1u;
  TFR(17) TFR(29) TFR(16) TFR(24)
  x0 += ks2; x1 += k0 + 2u;
  TFR(13) TFR(15) TFR(26) TFR(6)
  x0 += k0;  x1 += k1 + 3u;
  TFR(17) TFR(29) TFR(16) TFR(24)
  x0 += k1;  x1 += ks2 + 4u;
  TFR(13) TFR(15) TFR(26) TFR(6)
  x0 += ks2; x1 += k0 + 5u;
#undef TFR
  o0 = x0; o1 = x1;
}

struct Keys {
  uint32_t k1a[STEPS], k1b[STEPS];  // categorical (gumbel) keys per step
  uint32_t k2a[STEPS], k2b[STEPS];  // accept-uniform keys per step
};

// Fused table build: one block per state s, 512 threads (8 waves).
// Phase 1: h = relu(emb[s] @ W1 + b1), 8-way split-k in fp64 (order change
// vs R3 moves the sum by ~1 fp64 ulp -- no fp32 rounding flip in practice).
// Phase 2: each thread one output v: I[s][v] = h . W2[:,v] + b2[v], fully
// unrolled 64-FMA fp64 chain (64 L2 loads batched in flight).
// Also pthr[s] = 1-exp(-rowmax*0.01f) via the accept-path op chain.
__global__ __launch_bounds__(512)
void build_table(const float* __restrict__ emb,
                 const float* __restrict__ W1,
                 const float* __restrict__ b1,
                 const float* __restrict__ W2,
                 const float* __restrict__ b2,
                 float* __restrict__ I,
                 float* __restrict__ pthr) {
  const int s   = blockIdx.x;
  const int tid = threadIdx.x;
  __shared__ double part[8][HID];
  __shared__ double hd[HID];
  __shared__ float  redmax[8];

  const int hid = tid & (HID - 1);
  const int kq  = tid >> 6;               // 0..7
  const float* e = emb + s * EMB;
  double acc = 0.0;
#pragma unroll
  for (int k = kq; k < EMB; k += 8)
    acc += (double)e[k] * (double)W1[k * HID + hid];
  part[kq][hid] = acc;
  __syncthreads();
  if (kq == 0) {
    const double a = ((part[0][hid] + part[1][hid]) + (part[2][hid] + part[3][hid]))
                   + ((part[4][hid] + part[5][hid]) + (part[6][hid] + part[7][hid]));
    const float m = (float)a + b1[hid];
    hd[hid] = (double)(m > 0.0f ? m : 0.0f);   // relu, store as double once
  }
  __syncthreads();

  double acc2 = 0.0;
#pragma unroll
  for (int k = 0; k < HID; ++k)
    acc2 += hd[k] * (double)W2[k * VOCAB + tid];   // coalesced per k
  const float val = (float)acc2 + b2[tid];
  I[s * VOCAB + tid] = val;

  float lmax = val;                        // max is order-insensitive
  for (int off = 32; off > 0; off >>= 1)
    lmax = fmaxf(lmax, __shfl_xor(lmax, off, 64));
  if ((tid & 63) == 0) redmax[tid >> 6] = lmax;
  __syncthreads();
  if (tid == 0) {
    float m = redmax[0];
#pragma unroll
    for (int i = 1; i < 8; ++i) m = fmaxf(m, redmax[i]);
    const float z = (-m) * 0.01f;          // same chain as accept path
    pthr[s] = 1.0f - (float)exp((double)z);// monotone => safe reject bound
  }
}

// Markov kernel: one wave per 8 positions. All 40 (p,t) accept tests run in
// ONE ballot; loop only over candidate bits (avg ~0.9/wave). On an accepted
// jump, re-ballot that position's future bits against pthr[s_new].
__global__ __launch_bounds__(256)
void markov_kernel(const int* __restrict__ x_in,
                   const float* __restrict__ I,
                   const float* __restrict__ pthr,
                   int* __restrict__ x_out,
                   Keys K) {
  __shared__ float sp[VOCAB];
  sp[threadIdx.x]       = pthr[threadIdx.x];
  sp[threadIdx.x + 256] = pthr[threadIdx.x + 256];
  __syncthreads();

  const int gtid = blockIdx.x * blockDim.x + threadIdx.x;
  const int wave = gtid >> 6;
  const int lane = gtid & 63;
  const int base = wave * PPW;
  const float TINYF = 1.17549435e-38f;

  // Lane q < 40 holds the accept uniform for (p = q/5, t = q%5).
  const int qp = lane / 5;
  const int qt = lane - qp * 5;
  float u40 = 0.0f;
  if (lane < PPW * STEPS) {
    uint32_t w0, w1;
    tf2x32(K.k2a[qt], K.k2b[qt], 0u, (uint32_t)(base + qp), w0, w1);
    u40 = __uint_as_float((((w0 ^ w1) >> 9) | 0x3f800000u)) - 1.0f;
  }
  int scur = (lane < PPW) ? x_in[base + lane] : 0;   // lane p holds state of p

  // Initial candidate mask: u_q < pthr[s_p]  (state fixed unless accept).
  const int s_of_q = __shfl(scur, qp, 64);
  const bool cand = (lane < PPW * STEPS) && (u40 < sp[s_of_q]);
  unsigned long long mask = __ballot(cand);

  while (mask) {
    const int q = (int)__builtin_ctzll(mask);   // wave-uniform
    mask &= mask - 1;
    const int p = q / 5;
    const int t = q - p * 5;
    const int s = __builtin_amdgcn_readfirstlane(__shfl(scur, p, 64));

    // Full categorical (byte-identical to R1/R2/R3 path).
    const float* row = I + s * VOCAB;
    float best = -__builtin_inff();
    int bidx = 0;
    const uint32_t fbase = ((uint32_t)(base + p) << 9) + (uint32_t)lane;
#pragma unroll
    for (int j = 0; j < VOCAB / 64; ++j) {
      const int v = lane + (j << 6);
      uint32_t w0, w1;
      tf2x32(K.k1a[t], K.k1b[t], 0u, fbase + ((uint32_t)j << 6), w0, w1);
      const uint32_t bits = w0 ^ w1;
      float uf = __uint_as_float((bits >> 9) | 0x3f800000u) - 1.0f;
      if (uf == 0.0f) uf = TINYF;
      const float g = -logf(-logf(uf));
      if (v != s) {
        const float val = row[v] + g;
        if (val > best) { best = val; bidx = v; }
      }
    }
    for (int off = 32; off > 0; off >>= 1) {
      const float ob = __shfl_xor(best, off, 64);
      const int   oi = __shfl_xor(bidx, off, 64);
      if (ob > best || (ob == best && oi < bidx)) { best = ob; bidx = oi; }
    }
    bidx = __builtin_amdgcn_readfirstlane(bidx);
    const float rate = row[bidx];
    const float z = (-rate) * 0.01f;
    const float pacc = 1.0f - (float)exp((double)z);  // CR fp32 exp
    const float u = __shfl(u40, q, 64);
    if (u < pacc) {
      if (lane == p) scur = bidx;                     // accept jump
      // Re-evaluate this position's FUTURE steps under the new state.
      const unsigned long long fut =
          (((1ull << (p * 5 + 5)) - 1) & ~((1ull << (q + 1)) - 1));
      const float pnew = sp[bidx];                    // wave-uniform
      const unsigned long long nb = __ballot(u40 < pnew) & fut;
      mask = (mask & ~fut) | nb;
    }
  }
  if (lane < PPW) x_out[base + lane] = scur;
}

extern "C" void kernel_launch(void* const* d_in, const int* in_sizes, int n_in,
                              void* d_out, int out_size, void* d_ws, size_t ws_size,
                              hipStream_t stream) {
  const int*   x   = (const int*)d_in[0];
  const float* emb = (const float*)d_in[1];
  const float* W1  = (const float*)d_in[2];
  const float* b1  = (const float*)d_in[3];
  const float* W2  = (const float*)d_in[4];
  const float* b2  = (const float*)d_in[5];
  float* I    = (float*)d_ws;                        // 1 MiB
  float* pthr = (float*)d_ws + VOCAB * VOCAB;        // +2 KiB
  int* out = (int*)d_out;

  // Host-side key derivation (partitionable scheme):
  //   key(42) = (0,42); split -> S_t = tf(key,(0,t)); (k1,k2) = tf(S_t,(0,j))
  Keys K;
  for (int t = 0; t < STEPS; ++t) {
    uint32_t Sa, Sb;
    tf2x32(0u, 42u, 0u, (uint32_t)t, Sa, Sb);
    tf2x32(Sa, Sb, 0u, 0u, K.k1a[t], K.k1b[t]);
    tf2x32(Sa, Sb, 0u, 1u, K.k2a[t], K.k2b[t]);
  }

  build_table<<<VOCAB, 512, 0, stream>>>(emb, W1, b1, W2, b2, I, pthr);
  markov_kernel<<<(NWAVES * 64) / 256, 256, 0, stream>>>(x, I, pthr, out, K);
}